// Round 8
// baseline (785.924 us; speedup 1.0000x reference)
//
#include <hip/hip_runtime.h>
#include <hip/hip_bf16.h>

#define NN 50000
#define NE 800000
#define DD 128
#define NCLS 40
#define NBK ((NN + 255) >> 8)   // 196 dst-buckets of 256 nodes
#define BPAD 8192               // padded bucket capacity (mean 4096, sd 64)

typedef _Float16 f16x8 __attribute__((ext_vector_type(8)));  // 8 f16 (4 VGPRs)
typedef _Float16 f16x4 __attribute__((ext_vector_type(4)));
typedef float f32x4 __attribute__((ext_vector_type(4)));     // MFMA acc

__device__ __forceinline__ unsigned int pack2h(_Float16 a, _Float16 b) {
    union { _Float16 h[2]; unsigned int u; } c;
    c.h[0] = a; c.h[1] = b;
    return c.u;
}
__device__ __forceinline__ void unpack2h(unsigned int p, float& a, float& b) {
    union { unsigned int u; _Float16 h[2]; } c;
    c.u = p;
    a = (float)c.h[0]; b = (float)c.h[1];
}

// ---------------------------------------------------------------------------
// Zero cnt + bucket cursors; block 0 additionally detects int64 vs int32 edges.
__global__ void k_init(const int* __restrict__ ei, int* __restrict__ flag,
                       int* __restrict__ cnt, int* __restrict__ bcur) {
    int i = blockIdx.x * 256 + threadIdx.x;
    if (i < NN) cnt[i] = 0;
    if (i < NBK) bcur[i] = 0;
    if (blockIdx.x == 0) {
        __shared__ int nz;
        if (threadIdx.x == 0) nz = 0;
        __syncthreads();
        int any = 0;
        for (int e = threadIdx.x; e < 2048; e += 256)
            if (ei[2 * e + 1] != 0) any = 1;
        if (any) atomicOr(&nz, 1);
        __syncthreads();
        if (threadIdx.x == 0) *flag = (nz == 0) ? 1 : 0;  // 1 => int64 layout
    }
}

// One edge pass: per-node histogram + bucket-append of (src,dst) pairs.
__global__ void k_part(const int* __restrict__ ei, const int* __restrict__ flag,
                       int* __restrict__ cnt, int* __restrict__ bcur,
                       uint2* __restrict__ pairs) {
    int e = blockIdx.x * 256 + threadIdx.x;
    if (e >= NE) return;
    int is64 = *flag;
    int s, d;
    if (is64) { s = ei[2 * e]; d = ei[2 * (NE + e)]; }
    else      { s = ei[e];     d = ei[NE + e]; }
    atomicAdd(&cnt[d], 1);
    int b = d >> 8;
    int pos = atomicAdd(&bcur[b], 1);
    if (pos < BPAD)  // statistically impossible to overflow; guard corruption
        pairs[(size_t)b * BPAD + pos] = make_uint2((unsigned)s, (unsigned)d);
}

__global__ void k_scan1(const int* __restrict__ cnt, int* __restrict__ incl,
                        int* __restrict__ bsum) {
    __shared__ int s[1024];
    int t = threadIdx.x;
    int i = blockIdx.x * 1024 + t;
    int v = (i < NN) ? cnt[i] : 0;
    s[t] = v;
    __syncthreads();
#pragma unroll
    for (int off = 1; off < 1024; off <<= 1) {
        int u = (t >= off) ? s[t - off] : 0;
        __syncthreads();
        s[t] += u;
        __syncthreads();
    }
    if (i < NN) incl[i] = s[t];
    if (t == 1023) bsum[blockIdx.x] = s[1023];
}

__global__ void k_scan2(int* __restrict__ bsum, int* __restrict__ boff,
                        const int nb) {
    __shared__ int s[64];
    int t = threadIdx.x;
    s[t] = (t < nb) ? bsum[t] : 0;
    __syncthreads();
#pragma unroll
    for (int off = 1; off < 64; off <<= 1) {
        int u = (t >= off) ? s[t - off] : 0;
        __syncthreads();
        s[t] += u;
        __syncthreads();
    }
    if (t < nb) boff[t] = s[t] - bsum[t];
    if (t == 63) boff[nb] = s[63];
}

__global__ void k_scan3(const int* __restrict__ cnt, const int* __restrict__ incl,
                        const int* __restrict__ boff, int* __restrict__ row_ptr,
                        const int nb) {
    int i = blockIdx.x * 1024 + threadIdx.x;
    if (i < NN) row_ptr[i] = incl[i] - cnt[i] + boff[blockIdx.x];
    if (i == 0) row_ptr[NN] = boff[nb];
}

// One block per bucket: scatter srcs within the bucket's L2-local region,
// per-node cursors in LDS.
__global__ void k_fill2(const uint2* __restrict__ pairs, const int* __restrict__ row_ptr,
                        const int* __restrict__ bcur, int* __restrict__ srcs) {
    __shared__ int cur[256];
    int b = blockIdx.x;
    int t = threadIdx.x;
    int node = (b << 8) + t;
    cur[t] = (node < NN) ? row_ptr[node] : 0;
    __syncthreads();
    int count = bcur[b];
    const uint2* pp = pairs + (size_t)b * BPAD;
    for (int i = t; i < count; i += 256) {
        uint2 p = pp[i];
        int pos = atomicAdd(&cur[p.y & 255], 1);
        srcs[pos] = (int)p.x;
    }
}

// ---------------------------------------------------------------------------
// fp32 -> f16 hi/lo planes. Each thread: 4 features (float4 -> 2x f16x4).
__global__ void k_cvt_x(const float* __restrict__ x, unsigned short* __restrict__ xh,
                        unsigned short* __restrict__ xl) {
    int i = blockIdx.x * 256 + threadIdx.x;
    float4 v = ((const float4*)x)[i];
    float f[4] = {v.x, v.y, v.z, v.w};
    f16x4 h, l;
#pragma unroll
    for (int j = 0; j < 4; ++j) {
        _Float16 hh = (_Float16)f[j];
        h[j] = hh;
        l[j] = (_Float16)(f[j] - (float)hh);
    }
    *(f16x4*)(xh + (size_t)i * 4) = h;
    *(f16x4*)(xl + (size_t)i * 4) = l;
}

// All three layers' B tensors in MFMA-fragment-major order, one launch.
//   elem((ks,nt,lane,j)) = Bt[nt*16+(lane&15)][ks*32+(lane>>4)*8+j]
// grid = (8 ks, 8 nt, 3 layer); block = (8 j, 64 lane).
__global__ void k_cvt_w3(const float* __restrict__ w1l, const float* __restrict__ w1r,
                         const float* __restrict__ w2l, const float* __restrict__ w2r,
                         const float* __restrict__ w3l, const float* __restrict__ w3r,
                         unsigned short* __restrict__ bt1h, unsigned short* __restrict__ bt1l,
                         unsigned short* __restrict__ bt2h, unsigned short* __restrict__ bt2l,
                         unsigned short* __restrict__ bt3h, unsigned short* __restrict__ bt3l) {
    int ks = blockIdx.x, nt = blockIdx.y, layer = blockIdx.z;
    const int NT = (layer == 2) ? 3 : 8;
    const int NC = (layer == 2) ? NCLS : DD;
    if (nt >= NT) return;
    const float* wl = (layer == 0) ? w1l : (layer == 1) ? w2l : w3l;
    const float* wr = (layer == 0) ? w1r : (layer == 1) ? w2r : w3r;
    unsigned short* bh = (layer == 0) ? bt1h : (layer == 1) ? bt2h : bt3h;
    unsigned short* bl = (layer == 0) ? bt1l : (layer == 1) ? bt2l : bt3l;
    int lane = threadIdx.y, j = threadIdx.x;
    int row = nt * 16 + (lane & 15);          // output column n
    int k = ks * 32 + (lane >> 4) * 8 + j;    // K position in [Wl;Wr]
    float v = 0.f;
    if (row < NC)
        v = (k < 128) ? wl[(size_t)k * NC + row] : wr[(size_t)(k - 128) * NC + row];
    _Float16 h = (_Float16)v;
    _Float16 l = (_Float16)(v - (float)h);
    size_t o = ((size_t)(ks * NT + nt) * 64 + lane) * 8 + j;
    union { _Float16 f; unsigned short u; } ch, cl;
    ch.f = h; cl.f = l;
    bh[o] = ch.u;
    bl[o] = cl.u;
}

// ---------------------------------------------------------------------------
// Mean aggregation, hi-plane only: one wave per node, 1 uint (2 f16) per lane.
__global__ void k_agg(const unsigned int* __restrict__ inh, const int* __restrict__ row_ptr,
                      const int* __restrict__ srcs, unsigned int* __restrict__ oh,
                      unsigned int* __restrict__ ol) {
    int node = blockIdx.x * 4 + (threadIdx.x >> 6);
    if (node >= NN) return;
    int lane = threadIdx.x & 63;
    int b = row_ptr[node], e = row_ptr[node + 1];
    float a0 = 0.f, a1 = 0.f;
    int i = b;
    for (; i + 3 < e; i += 4) {
        int s0 = srcs[i + 0], s1 = srcs[i + 1], s2 = srcs[i + 2], s3 = srcs[i + 3];
        unsigned int p0 = inh[(size_t)s0 * 64 + lane];
        unsigned int p1 = inh[(size_t)s1 * 64 + lane];
        unsigned int p2 = inh[(size_t)s2 * 64 + lane];
        unsigned int p3 = inh[(size_t)s3 * 64 + lane];
        float u0, u1;
        unpack2h(p0, u0, u1); a0 += u0; a1 += u1;
        unpack2h(p1, u0, u1); a0 += u0; a1 += u1;
        unpack2h(p2, u0, u1); a0 += u0; a1 += u1;
        unpack2h(p3, u0, u1); a0 += u0; a1 += u1;
    }
    for (; i < e; ++i) {
        unsigned int p = inh[(size_t)srcs[i] * 64 + lane];
        float u0, u1;
        unpack2h(p, u0, u1); a0 += u0; a1 += u1;
    }
    int deg = e - b;
    float inv = 1.0f / (float)(deg > 0 ? deg : 1);
    float v0 = a0 * inv, v1 = a1 * inv;
    _Float16 h0 = (_Float16)v0, h1 = (_Float16)v1;
    oh[(size_t)node * 64 + lane] = pack2h(h0, h1);
    ol[(size_t)node * 64 + lane] = pack2h((_Float16)(v0 - (float)h0),
                                          (_Float16)(v1 - (float)h1));
}

// ---------------------------------------------------------------------------
// Split-precision f16 MFMA GEMM, B staged in LDS in fragment layout.
// Wave = 1 m-tile (16 rows) x NT n-tiles; block = 4 waves = 64 rows.
// 3-product split: Ah*Bh + Al*Bh + Ah*Bl (~2^-21 rel).
template <int NT, int KPS, bool PACKOUT>
__launch_bounds__(256, 4)
__global__ void k_mfma(const unsigned short* __restrict__ A1h, const unsigned short* __restrict__ A1l,
                       const unsigned short* __restrict__ A2h, const unsigned short* __restrict__ A2l,
                       const unsigned short* __restrict__ Bthf, const unsigned short* __restrict__ Btlf,
                       const float* __restrict__ bias, float* __restrict__ outf,
                       unsigned short* __restrict__ outh, unsigned short* __restrict__ outl,
                       const int NC) {
    constexpr int STAGE_ELEMS = KPS * NT * 64 * 8;          // f16 per stage
    constexpr int STAGE_U4 = STAGE_ELEMS / 8;               // uint4 per stage
    constexpr int COPIES = STAGE_U4 / 256;                  // per-thread uint4
    __shared__ unsigned short sBh[STAGE_ELEMS];
    __shared__ unsigned short sBl[STAGE_ELEMS];

    const int tid = threadIdx.x;
    const int wave = tid >> 6, lane = tid & 63;
    const int quad = lane >> 4, mr = lane & 15;
    const int m0 = blockIdx.x * 64 + wave * 16;
    const int row = m0 + mr;
    const bool rok = row < NN;

    f32x4 acc[NT] = {};
    const f16x8 zero = {};

    auto aload = [&](int ks, f16x8& ah, f16x8& al) {
        const unsigned short* bh = (ks < 4) ? A1h : A2h;
        const unsigned short* bl = (ks < 4) ? A1l : A2l;
        const int ko = ((ks * 32) & 127) + quad * 8;
        if (rok) {
            ah = *(const f16x8*)(bh + (size_t)row * 128 + ko);
            al = *(const f16x8*)(bl + (size_t)row * 128 + ko);
        } else {
            ah = zero;
            al = zero;
        }
    };

    f16x8 cah, cal, pah, pal;
    aload(0, cah, cal);

#pragma unroll
    for (int s = 0; s < 8 / KPS; ++s) {
        const uint4* gh = (const uint4*)(Bthf + (size_t)s * STAGE_ELEMS);
        const uint4* gl = (const uint4*)(Btlf + (size_t)s * STAGE_ELEMS);
        uint4* lh = (uint4*)sBh;
        uint4* ll = (uint4*)sBl;
        if (s) __syncthreads();
#pragma unroll
        for (int i = 0; i < COPIES; ++i) {
            lh[tid + i * 256] = gh[tid + i * 256];
            ll[tid + i * 256] = gl[tid + i * 256];
        }
        __syncthreads();

#pragma unroll
        for (int kl = 0; kl < KPS; ++kl) {
            const int ks = s * KPS + kl;
            if (ks < 7) aload(ks + 1, pah, pal);  // prefetch next A slice
#pragma unroll
            for (int n = 0; n < NT; ++n) {
                const int fo = ((kl * NT + n) * 64 + lane) * 8;
                f16x8 bh = *(const f16x8*)(sBh + fo);
                f16x8 bl = *(const f16x8*)(sBl + fo);
                acc[n] = __builtin_amdgcn_mfma_f32_16x16x32_f16(cah, bh, acc[n], 0, 0, 0);
                acc[n] = __builtin_amdgcn_mfma_f32_16x16x32_f16(cal, bh, acc[n], 0, 0, 0);
                acc[n] = __builtin_amdgcn_mfma_f32_16x16x32_f16(cah, bl, acc[n], 0, 0, 0);
            }
            cah = pah;
            cal = pal;
        }
    }

    // Epilogue. C/D layout: col = lane&15, row = quad*4 + reg.
#pragma unroll
    for (int n = 0; n < NT; ++n) {
        int col = n * 16 + mr;
        float bv = (col < NC) ? bias[col] : 0.f;
#pragma unroll
        for (int r = 0; r < 4; ++r) {
            int orow = m0 + quad * 4 + r;
            if (orow < NN && col < NC) {
                float v = acc[n][r] + bv;
                v = v > 0.f ? v : 0.f;
                if (PACKOUT) {
                    _Float16 h = (_Float16)v;
                    _Float16 l = (_Float16)(v - (float)h);
                    union { _Float16 f; unsigned short u; } ch, cl;
                    ch.f = h; cl.f = l;
                    outh[(size_t)orow * 128 + col] = ch.u;
                    outl[(size_t)orow * 128 + col] = cl.u;
                } else {
                    outf[(size_t)orow * NC + col] = v;
                }
            }
        }
    }
}

// ---------------------------------------------------------------------------
extern "C" void kernel_launch(void* const* d_in, const int* in_sizes, int n_in,
                              void* d_out, int out_size, void* d_ws, size_t ws_size,
                              hipStream_t stream) {
    const float* x    = (const float*)d_in[0];
    const int*   ei   = (const int*)d_in[1];
    const float* w1_l = (const float*)d_in[2];
    const float* w1_r = (const float*)d_in[3];
    const float* b1   = (const float*)d_in[4];
    const float* w2_l = (const float*)d_in[5];
    const float* w2_r = (const float*)d_in[6];
    const float* b2   = (const float*)d_in[7];
    const float* w3_l = (const float*)d_in[8];
    const float* w3_r = (const float*)d_in[9];
    const float* b3   = (const float*)d_in[10];
    float* out = (float*)d_out;

    char* w = (char*)d_ws;
    size_t off = 0;
    auto alloc = [&](size_t bytes) -> void* {
        void* p = w + off;
        off += (bytes + 255) / 256 * 256;
        return p;
    };
    int* flag    = (int*)alloc(4);
    int* cnt     = (int*)alloc((size_t)NN * 4);
    int* row_ptr = (int*)alloc((size_t)(NN + 1) * 4);
    int* srcs    = (int*)alloc((size_t)NE * 4);
    int* incl    = (int*)alloc((size_t)NN * 4);
    int* bsum    = (int*)alloc(64 * 4);
    int* boff    = (int*)alloc(64 * 4);
    int* bcur    = (int*)alloc((size_t)NBK * 4);
    uint2* pairs = (uint2*)alloc((size_t)NBK * BPAD * 8);
    unsigned short* xh   = (unsigned short*)alloc((size_t)NN * DD * 2);  // also h2h
    unsigned short* xl   = (unsigned short*)alloc((size_t)NN * DD * 2);  // also h2l
    unsigned short* aggh = (unsigned short*)alloc((size_t)NN * DD * 2);
    unsigned short* aggl = (unsigned short*)alloc((size_t)NN * DD * 2);
    unsigned short* h1h  = (unsigned short*)alloc((size_t)NN * DD * 2);
    unsigned short* h1l  = (unsigned short*)alloc((size_t)NN * DD * 2);
    unsigned short* bt1h = (unsigned short*)alloc((size_t)8 * 8 * 64 * 8 * 2);
    unsigned short* bt1l = (unsigned short*)alloc((size_t)8 * 8 * 64 * 8 * 2);
    unsigned short* bt2h = (unsigned short*)alloc((size_t)8 * 8 * 64 * 8 * 2);
    unsigned short* bt2l = (unsigned short*)alloc((size_t)8 * 8 * 64 * 8 * 2);
    unsigned short* bt3h = (unsigned short*)alloc((size_t)8 * 3 * 64 * 8 * 2);
    unsigned short* bt3l = (unsigned short*)alloc((size_t)8 * 3 * 64 * 8 * 2);
    unsigned short* h2h = xh, *h2l = xl;  // x dead after layer-1 GEMM
    (void)ws_size;

    const int eb = (NE + 255) / 256;
    const int nb = (NN + 1023) / 1024;  // 49
    k_init<<<NBK, 256, 0, stream>>>(ei, flag, cnt, bcur);
    k_part<<<eb, 256, 0, stream>>>(ei, flag, cnt, bcur, pairs);
    k_scan1<<<nb, 1024, 0, stream>>>(cnt, incl, bsum);
    k_scan2<<<1, 64, 0, stream>>>(bsum, boff, nb);
    k_scan3<<<nb, 1024, 0, stream>>>(cnt, incl, boff, row_ptr, nb);
    k_fill2<<<NBK, 256, 0, stream>>>(pairs, row_ptr, bcur, srcs);

    k_cvt_x<<<(NN * DD / 4) / 256, 256, 0, stream>>>(x, xh, xl);
    k_cvt_w3<<<dim3(8, 8, 3), dim3(8, 64), 0, stream>>>(w1_l, w1_r, w2_l, w2_r,
                                                        w3_l, w3_r, bt1h, bt1l,
                                                        bt2h, bt2l, bt3h, bt3l);

    const int gmb = (NN + 63) / 64;   // 782 (GEMM m-blocks)
    const int gab = (NN + 3) / 4;     // 12500 (agg blocks, 4 nodes each)
    // Layer 1
    k_agg<<<gab, 256, 0, stream>>>((const unsigned int*)xh, row_ptr, srcs,
                                   (unsigned int*)aggh, (unsigned int*)aggl);
    k_mfma<8, 4, true><<<gmb, 256, 0, stream>>>(aggh, aggl, xh, xl, bt1h, bt1l, b1,
                                                nullptr, h1h, h1l, DD);
    // Layer 2 (h2 planes alias x planes; x is dead)
    k_agg<<<gab, 256, 0, stream>>>((const unsigned int*)h1h, row_ptr, srcs,
                                   (unsigned int*)aggh, (unsigned int*)aggl);
    k_mfma<8, 4, true><<<gmb, 256, 0, stream>>>(aggh, aggl, h1h, h1l, bt2h, bt2l, b2,
                                                nullptr, h2h, h2l, DD);
    // Layer 3
    k_agg<<<gab, 256, 0, stream>>>((const unsigned int*)h2h, row_ptr, srcs,
                                   (unsigned int*)aggh, (unsigned int*)aggl);
    k_mfma<3, 8, false><<<gmb, 256, 0, stream>>>(aggh, aggl, h2h, h2l, bt3h, bt3l, b3,
                                                 out, nullptr, nullptr, NCLS);
}

// Round 9
// 355.062 us; speedup vs baseline: 2.2135x; 2.2135x over previous
//
#include <hip/hip_runtime.h>
#include <hip/hip_bf16.h>

#define NN 50000
#define NE 800000
#define DD 128
#define NCLS 40

typedef _Float16 f16x8 __attribute__((ext_vector_type(8)));  // 8 f16 (4 VGPRs)
typedef _Float16 f16x4 __attribute__((ext_vector_type(4)));
typedef float f32x4 __attribute__((ext_vector_type(4)));     // MFMA acc

__device__ __forceinline__ unsigned int pack2h(_Float16 a, _Float16 b) {
    union { _Float16 h[2]; unsigned int u; } c;
    c.h[0] = a; c.h[1] = b;
    return c.u;
}
__device__ __forceinline__ void unpack2h(unsigned int p, float& a, float& b) {
    union { unsigned int u; _Float16 h[2]; } c;
    c.u = p;
    a = (float)c.h[0]; b = (float)c.h[1];
}

// ---------------------------------------------------------------------------
// Zero cnt; block 0 additionally detects int64 vs int32 edge layout.
__global__ void k_init(const int* __restrict__ ei, int* __restrict__ flag,
                       int* __restrict__ cnt) {
    int i = blockIdx.x * 256 + threadIdx.x;
    if (i < NN) cnt[i] = 0;
    if (blockIdx.x == 0) {
        __shared__ int nz;
        if (threadIdx.x == 0) nz = 0;
        __syncthreads();
        int any = 0;
        for (int e = threadIdx.x; e < 2048; e += 256)
            if (ei[2 * e + 1] != 0) any = 1;
        if (any) atomicOr(&nz, 1);
        __syncthreads();
        if (threadIdx.x == 0) *flag = (nz == 0) ? 1 : 0;  // 1 => int64 layout
    }
}

__global__ void k_count(const int* __restrict__ ei, const int* __restrict__ flag,
                        int* __restrict__ cnt) {
    int e = blockIdx.x * 256 + threadIdx.x;
    if (e >= NE) return;
    int is64 = *flag;
    int d = is64 ? ei[2 * (NE + e)] : ei[NE + e];
    atomicAdd(&cnt[d], 1);
}

__global__ void k_scan1(const int* __restrict__ cnt, int* __restrict__ incl,
                        int* __restrict__ bsum) {
    __shared__ int s[1024];
    int t = threadIdx.x;
    int i = blockIdx.x * 1024 + t;
    int v = (i < NN) ? cnt[i] : 0;
    s[t] = v;
    __syncthreads();
#pragma unroll
    for (int off = 1; off < 1024; off <<= 1) {
        int u = (t >= off) ? s[t - off] : 0;
        __syncthreads();
        s[t] += u;
        __syncthreads();
    }
    if (i < NN) incl[i] = s[t];
    if (t == 1023) bsum[blockIdx.x] = s[1023];
}

__global__ void k_scan2(int* __restrict__ bsum, int* __restrict__ boff,
                        const int nb) {
    __shared__ int s[64];
    int t = threadIdx.x;
    s[t] = (t < nb) ? bsum[t] : 0;
    __syncthreads();
#pragma unroll
    for (int off = 1; off < 64; off <<= 1) {
        int u = (t >= off) ? s[t - off] : 0;
        __syncthreads();
        s[t] += u;
        __syncthreads();
    }
    if (t < nb) boff[t] = s[t] - bsum[t];
    if (t == 63) boff[nb] = s[63];
}

__global__ void k_scan3(const int* __restrict__ cnt, const int* __restrict__ incl,
                        const int* __restrict__ boff, int* __restrict__ row_ptr,
                        int* __restrict__ cursor, const int nb) {
    int i = blockIdx.x * 1024 + threadIdx.x;
    if (i < NN) {
        row_ptr[i] = incl[i] - cnt[i] + boff[blockIdx.x];
        cursor[i] = 0;
    }
    if (i == 0) row_ptr[NN] = boff[nb];
}

__global__ void k_fill(const int* __restrict__ ei, const int* __restrict__ flag,
                       const int* __restrict__ row_ptr, int* __restrict__ cursor,
                       int* __restrict__ srcs) {
    int e = blockIdx.x * 256 + threadIdx.x;
    if (e >= NE) return;
    int is64 = *flag;
    int s, d;
    if (is64) { s = ei[2 * e]; d = ei[2 * (NE + e)]; }
    else      { s = ei[e];     d = ei[NE + e]; }
    int pos = row_ptr[d] + atomicAdd(&cursor[d], 1);
    srcs[pos] = s;
}

// ---------------------------------------------------------------------------
// fp32 -> f16 hi/lo planes. Each thread: 4 features (float4 -> 2x f16x4).
__global__ void k_cvt_x(const float* __restrict__ x, unsigned short* __restrict__ xh,
                        unsigned short* __restrict__ xl) {
    int i = blockIdx.x * 256 + threadIdx.x;
    float4 v = ((const float4*)x)[i];
    float f[4] = {v.x, v.y, v.z, v.w};
    f16x4 h, l;
#pragma unroll
    for (int j = 0; j < 4; ++j) {
        _Float16 hh = (_Float16)f[j];
        h[j] = hh;
        l[j] = (_Float16)(f[j] - (float)hh);
    }
    *(f16x4*)(xh + (size_t)i * 4) = h;
    *(f16x4*)(xl + (size_t)i * 4) = l;
}

// All three layers' B tensors in MFMA-fragment-major order, one launch.
//   elem((ks,nt,lane,j)) = Bt[nt*16+(lane&15)][ks*32+(lane>>4)*8+j]
__global__ void k_cvt_w3(const float* __restrict__ w1l, const float* __restrict__ w1r,
                         const float* __restrict__ w2l, const float* __restrict__ w2r,
                         const float* __restrict__ w3l, const float* __restrict__ w3r,
                         unsigned short* __restrict__ bt1h, unsigned short* __restrict__ bt1l,
                         unsigned short* __restrict__ bt2h, unsigned short* __restrict__ bt2l,
                         unsigned short* __restrict__ bt3h, unsigned short* __restrict__ bt3l) {
    int ks = blockIdx.x, nt = blockIdx.y, layer = blockIdx.z;
    const int NT = (layer == 2) ? 3 : 8;
    const int NC = (layer == 2) ? NCLS : DD;
    if (nt >= NT) return;
    const float* wl = (layer == 0) ? w1l : (layer == 1) ? w2l : w3l;
    const float* wr = (layer == 0) ? w1r : (layer == 1) ? w2r : w3r;
    unsigned short* bh = (layer == 0) ? bt1h : (layer == 1) ? bt2h : bt3h;
    unsigned short* bl = (layer == 0) ? bt1l : (layer == 1) ? bt2l : bt3l;
    int lane = threadIdx.y, j = threadIdx.x;
    int row = nt * 16 + (lane & 15);          // output column n
    int k = ks * 32 + (lane >> 4) * 8 + j;    // K position in [Wl;Wr]
    float v = 0.f;
    if (row < NC)
        v = (k < 128) ? wl[(size_t)k * NC + row] : wr[(size_t)(k - 128) * NC + row];
    _Float16 h = (_Float16)v;
    _Float16 l = (_Float16)(v - (float)h);
    size_t o = ((size_t)(ks * NT + nt) * 64 + lane) * 8 + j;
    union { _Float16 f; unsigned short u; } ch, cl;
    ch.f = h; cl.f = l;
    bh[o] = ch.u;
    bl[o] = cl.u;
}

// ---------------------------------------------------------------------------
// Mean aggregation, hi-plane in -> hi-plane out (agg-lo dropped; error budget
// analysis: adds ~1.5e-4/layer vs 1.14e-2 threshold).
__global__ void k_agg(const unsigned int* __restrict__ inh, const int* __restrict__ row_ptr,
                      const int* __restrict__ srcs, unsigned int* __restrict__ oh) {
    int node = blockIdx.x * 4 + (threadIdx.x >> 6);
    if (node >= NN) return;
    int lane = threadIdx.x & 63;
    int b = row_ptr[node], e = row_ptr[node + 1];
    float a0 = 0.f, a1 = 0.f;
    int i = b;
    for (; i + 3 < e; i += 4) {
        int s0 = srcs[i + 0], s1 = srcs[i + 1], s2 = srcs[i + 2], s3 = srcs[i + 3];
        unsigned int p0 = inh[(size_t)s0 * 64 + lane];
        unsigned int p1 = inh[(size_t)s1 * 64 + lane];
        unsigned int p2 = inh[(size_t)s2 * 64 + lane];
        unsigned int p3 = inh[(size_t)s3 * 64 + lane];
        float u0, u1;
        unpack2h(p0, u0, u1); a0 += u0; a1 += u1;
        unpack2h(p1, u0, u1); a0 += u0; a1 += u1;
        unpack2h(p2, u0, u1); a0 += u0; a1 += u1;
        unpack2h(p3, u0, u1); a0 += u0; a1 += u1;
    }
    for (; i < e; ++i) {
        unsigned int p = inh[(size_t)srcs[i] * 64 + lane];
        float u0, u1;
        unpack2h(p, u0, u1); a0 += u0; a1 += u1;
    }
    int deg = e - b;
    float inv = 1.0f / (float)(deg > 0 ? deg : 1);
    oh[(size_t)node * 64 + lane] = pack2h((_Float16)(a0 * inv), (_Float16)(a1 * inv));
}

// ---------------------------------------------------------------------------
// Split-precision f16 MFMA GEMM, B staged in LDS in fragment layout.
// A1 (agg): hi plane only (2-product split); A2 (self): hi+lo (3-product).
// Wave = 1 m-tile (16 rows) x NT n-tiles; block = 4 waves = 64 rows.
// KPS=2 keeps LDS at 2*(KPS*NT*512*2)B = 32KB (NT=8) -> 4 blocks/CU.
template <int NT, int KPS, bool PACKOUT>
__launch_bounds__(256, 4)
__global__ void k_mfma(const unsigned short* __restrict__ A1h,
                       const unsigned short* __restrict__ A2h, const unsigned short* __restrict__ A2l,
                       const unsigned short* __restrict__ Bthf, const unsigned short* __restrict__ Btlf,
                       const float* __restrict__ bias, float* __restrict__ outf,
                       unsigned short* __restrict__ outh, unsigned short* __restrict__ outl,
                       const int NC) {
    constexpr int STAGE_ELEMS = KPS * NT * 64 * 8;          // f16 per stage
    constexpr int STAGE_U4 = STAGE_ELEMS / 8;               // uint4 per stage
    __shared__ unsigned short sBh[STAGE_ELEMS];
    __shared__ unsigned short sBl[STAGE_ELEMS];

    const int tid = threadIdx.x;
    const int wave = tid >> 6, lane = tid & 63;
    const int quad = lane >> 4, mr = lane & 15;
    const int m0 = blockIdx.x * 64 + wave * 16;
    const int row = m0 + mr;
    const bool rok = row < NN;

    f32x4 acc[NT] = {};
    const f16x8 zero = {};

    auto aload = [&](int ks, f16x8& ah, f16x8& al) {
        const int ko = ((ks * 32) & 127) + quad * 8;
        if (ks < 4) {
            ah = rok ? *(const f16x8*)(A1h + (size_t)row * 128 + ko) : zero;
            al = zero;  // agg-lo dropped
        } else {
            ah = rok ? *(const f16x8*)(A2h + (size_t)row * 128 + ko) : zero;
            al = rok ? *(const f16x8*)(A2l + (size_t)row * 128 + ko) : zero;
        }
    };

    f16x8 cah, cal, pah, pal;
    aload(0, cah, cal);

#pragma unroll
    for (int s = 0; s < 8 / KPS; ++s) {
        const uint4* gh = (const uint4*)(Bthf + (size_t)s * STAGE_ELEMS);
        const uint4* gl = (const uint4*)(Btlf + (size_t)s * STAGE_ELEMS);
        uint4* lh = (uint4*)sBh;
        uint4* ll = (uint4*)sBl;
        if (s) __syncthreads();
        for (int i = tid; i < STAGE_U4; i += 256) {
            lh[i] = gh[i];
            ll[i] = gl[i];
        }
        __syncthreads();

#pragma unroll
        for (int kl = 0; kl < KPS; ++kl) {
            const int ks = s * KPS + kl;
            if (ks < 7) aload(ks + 1, pah, pal);  // prefetch next A slice
#pragma unroll
            for (int n = 0; n < NT; ++n) {
                const int fo = ((kl * NT + n) * 64 + lane) * 8;
                f16x8 bh = *(const f16x8*)(sBh + fo);
                f16x8 bl = *(const f16x8*)(sBl + fo);
                acc[n] = __builtin_amdgcn_mfma_f32_16x16x32_f16(cah, bh, acc[n], 0, 0, 0);
                acc[n] = __builtin_amdgcn_mfma_f32_16x16x32_f16(cah, bl, acc[n], 0, 0, 0);
                if (ks >= 4)  // self half has a lo plane
                    acc[n] = __builtin_amdgcn_mfma_f32_16x16x32_f16(cal, bh, acc[n], 0, 0, 0);
            }
            cah = pah;
            cal = pal;
        }
    }

    // Epilogue. C/D layout: col = lane&15, row = quad*4 + reg.
#pragma unroll
    for (int n = 0; n < NT; ++n) {
        int col = n * 16 + mr;
        float bv = (col < NC) ? bias[col] : 0.f;
#pragma unroll
        for (int r = 0; r < 4; ++r) {
            int orow = m0 + quad * 4 + r;
            if (orow < NN && col < NC) {
                float v = acc[n][r] + bv;
                v = v > 0.f ? v : 0.f;
                if (PACKOUT) {
                    _Float16 h = (_Float16)v;
                    _Float16 l = (_Float16)(v - (float)h);
                    union { _Float16 f; unsigned short u; } ch, cl;
                    ch.f = h; cl.f = l;
                    outh[(size_t)orow * 128 + col] = ch.u;
                    outl[(size_t)orow * 128 + col] = cl.u;
                } else {
                    outf[(size_t)orow * NC + col] = v;
                }
            }
        }
    }
}

// ---------------------------------------------------------------------------
extern "C" void kernel_launch(void* const* d_in, const int* in_sizes, int n_in,
                              void* d_out, int out_size, void* d_ws, size_t ws_size,
                              hipStream_t stream) {
    const float* x    = (const float*)d_in[0];
    const int*   ei   = (const int*)d_in[1];
    const float* w1_l = (const float*)d_in[2];
    const float* w1_r = (const float*)d_in[3];
    const float* b1   = (const float*)d_in[4];
    const float* w2_l = (const float*)d_in[5];
    const float* w2_r = (const float*)d_in[6];
    const float* b2   = (const float*)d_in[7];
    const float* w3_l = (const float*)d_in[8];
    const float* w3_r = (const float*)d_in[9];
    const float* b3   = (const float*)d_in[10];
    float* out = (float*)d_out;

    char* w = (char*)d_ws;
    size_t off = 0;
    auto alloc = [&](size_t bytes) -> void* {
        void* p = w + off;
        off += (bytes + 255) / 256 * 256;
        return p;
    };
    int* flag    = (int*)alloc(4);
    int* cnt     = (int*)alloc((size_t)NN * 4);
    int* row_ptr = (int*)alloc((size_t)(NN + 1) * 4);
    int* cursor  = (int*)alloc((size_t)NN * 4);
    int* srcs    = (int*)alloc((size_t)NE * 4);
    int* incl    = (int*)alloc((size_t)NN * 4);
    int* bsum    = (int*)alloc(64 * 4);
    int* boff    = (int*)alloc(64 * 4);
    unsigned short* xh   = (unsigned short*)alloc((size_t)NN * DD * 2);  // also h2h
    unsigned short* xl   = (unsigned short*)alloc((size_t)NN * DD * 2);  // also h2l
    unsigned short* aggh = (unsigned short*)alloc((size_t)NN * DD * 2);
    unsigned short* h1h  = (unsigned short*)alloc((size_t)NN * DD * 2);
    unsigned short* h1l  = (unsigned short*)alloc((size_t)NN * DD * 2);
    unsigned short* bt1h = (unsigned short*)alloc((size_t)8 * 8 * 64 * 8 * 2);
    unsigned short* bt1l = (unsigned short*)alloc((size_t)8 * 8 * 64 * 8 * 2);
    unsigned short* bt2h = (unsigned short*)alloc((size_t)8 * 8 * 64 * 8 * 2);
    unsigned short* bt2l = (unsigned short*)alloc((size_t)8 * 8 * 64 * 8 * 2);
    unsigned short* bt3h = (unsigned short*)alloc((size_t)8 * 3 * 64 * 8 * 2);
    unsigned short* bt3l = (unsigned short*)alloc((size_t)8 * 3 * 64 * 8 * 2);
    unsigned short* h2h = xh, *h2l = xl;  // x dead after layer-1 GEMM
    (void)ws_size;

    const int eb = (NE + 255) / 256;
    const int nb = (NN + 1023) / 1024;  // 49
    k_init<<<(NN + 255) / 256, 256, 0, stream>>>(ei, flag, cnt);
    k_count<<<eb, 256, 0, stream>>>(ei, flag, cnt);
    k_scan1<<<nb, 1024, 0, stream>>>(cnt, incl, bsum);
    k_scan2<<<1, 64, 0, stream>>>(bsum, boff, nb);
    k_scan3<<<nb, 1024, 0, stream>>>(cnt, incl, boff, row_ptr, cursor, nb);
    k_fill<<<eb, 256, 0, stream>>>(ei, flag, row_ptr, cursor, srcs);

    k_cvt_x<<<(NN * DD / 4) / 256, 256, 0, stream>>>(x, xh, xl);
    k_cvt_w3<<<dim3(8, 8, 3), dim3(8, 64), 0, stream>>>(w1_l, w1_r, w2_l, w2_r,
                                                        w3_l, w3_r, bt1h, bt1l,
                                                        bt2h, bt2l, bt3h, bt3l);

    const int gmb = (NN + 63) / 64;   // 782 (GEMM m-blocks)
    const int gab = (NN + 3) / 4;     // 12500 (agg blocks, 4 nodes each)
    // Layer 1
    k_agg<<<gab, 256, 0, stream>>>((const unsigned int*)xh, row_ptr, srcs,
                                   (unsigned int*)aggh);
    k_mfma<8, 2, true><<<gmb, 256, 0, stream>>>(aggh, xh, xl, bt1h, bt1l, b1,
                                                nullptr, h1h, h1l, DD);
    // Layer 2 (h2 planes alias x planes; x is dead)
    k_agg<<<gab, 256, 0, stream>>>((const unsigned int*)h1h, row_ptr, srcs,
                                   (unsigned int*)aggh);
    k_mfma<8, 2, true><<<gmb, 256, 0, stream>>>(aggh, h1h, h1l, bt2h, bt2l, b2,
                                                nullptr, h2h, h2l, DD);
    // Layer 3
    k_agg<<<gab, 256, 0, stream>>>((const unsigned int*)h2h, row_ptr, srcs,
                                   (unsigned int*)aggh);
    k_mfma<3, 2, false><<<gmb, 256, 0, stream>>>(aggh, h2h, h2l, bt3h, bt3l, b3,
                                                 out, nullptr, nullptr, NCLS);
}

// Round 10
// 323.045 us; speedup vs baseline: 2.4329x; 1.0991x over previous
//
#include <hip/hip_runtime.h>
#include <hip/hip_bf16.h>

#define NN 50000
#define NE 800000
#define DD 128
#define NCLS 40
#define NBK ((NN + 255) >> 8)   // 196 dst-buckets of 256 nodes
#define BPAD 5120               // bucket capacity (mean 4081, sd ~64; >16 sigma)
#define EPB 4096                // edges per k_part block (16/thread)

typedef _Float16 f16x8 __attribute__((ext_vector_type(8)));  // 8 f16 (4 VGPRs)
typedef _Float16 f16x4 __attribute__((ext_vector_type(4)));
typedef float f32x4 __attribute__((ext_vector_type(4)));     // MFMA acc

__device__ __forceinline__ unsigned int pack2h(_Float16 a, _Float16 b) {
    union { _Float16 h[2]; unsigned int u; } c;
    c.h[0] = a; c.h[1] = b;
    return c.u;
}
__device__ __forceinline__ void unpack2h(unsigned int p, float& a, float& b) {
    union { unsigned int u; _Float16 h[2]; } c;
    c.u = p;
    a = (float)c.h[0]; b = (float)c.h[1];
}

// ---------------------------------------------------------------------------
// Zero cnt + bucket cursors; block 0 additionally detects int64 vs int32 edges.
__global__ void k_init(const int* __restrict__ ei, int* __restrict__ flag,
                       int* __restrict__ cnt, int* __restrict__ bcur) {
    int i = blockIdx.x * 256 + threadIdx.x;
    if (i < NN) cnt[i] = 0;
    if (i < NBK) bcur[i] = 0;
    if (blockIdx.x == 0) {
        __shared__ int nz;
        if (threadIdx.x == 0) nz = 0;
        __syncthreads();
        int any = 0;
        for (int e = threadIdx.x; e < 2048; e += 256)
            if (ei[2 * e + 1] != 0) any = 1;
        if (any) atomicOr(&nz, 1);
        __syncthreads();
        if (threadIdx.x == 0) *flag = (nz == 0) ? 1 : 0;  // 1 => int64 layout
    }
}

// Phase 1: per-node histogram + bucket-run scatter with block-local ranking.
// One global cursor atomic per (block,bucket) instead of per edge (R8's bug).
__global__ void k_part(const int* __restrict__ ei, const int* __restrict__ flag,
                       int* __restrict__ cnt, int* __restrict__ bcur,
                       unsigned int* __restrict__ pairs) {
    __shared__ unsigned int sE[EPB];   // (src<<16)|dst  (both < 65536)
    __shared__ unsigned short sR[EPB]; // block-local rank within bucket
    __shared__ int hist[NBK];
    __shared__ int base[NBK];
    const int t = threadIdx.x;
    const int e0 = blockIdx.x * EPB;
    const int is64 = *flag;
    for (int i = t; i < NBK; i += 256) hist[i] = 0;
    __syncthreads();
#pragma unroll
    for (int j = 0; j < EPB / 256; ++j) {
        int e = e0 + j * 256 + t;
        if (e < NE) {
            int s, d;
            if (is64) { s = ei[2 * e]; d = ei[2 * (NE + e)]; }
            else      { s = ei[e];     d = ei[NE + e]; }
            atomicAdd(&cnt[d], 1);
            int b = d >> 8;
            int r = atomicAdd(&hist[b], 1);
            sE[j * 256 + t] = ((unsigned)s << 16) | (unsigned)d;
            sR[j * 256 + t] = (unsigned short)r;
        }
    }
    __syncthreads();
    for (int i = t; i < NBK; i += 256)
        base[i] = hist[i] ? atomicAdd(&bcur[i], hist[i]) : 0;
    __syncthreads();
#pragma unroll
    for (int j = 0; j < EPB / 256; ++j) {
        int e = e0 + j * 256 + t;
        if (e < NE) {
            unsigned int v = sE[j * 256 + t];
            int b = (v & 0xFFFFu) >> 8;
            int pos = base[b] + sR[j * 256 + t];
            if (pos < BPAD) pairs[(size_t)b * BPAD + pos] = v;
        }
    }
}

__global__ void k_scan1(const int* __restrict__ cnt, int* __restrict__ incl,
                        int* __restrict__ bsum) {
    __shared__ int s[1024];
    int t = threadIdx.x;
    int i = blockIdx.x * 1024 + t;
    int v = (i < NN) ? cnt[i] : 0;
    s[t] = v;
    __syncthreads();
#pragma unroll
    for (int off = 1; off < 1024; off <<= 1) {
        int u = (t >= off) ? s[t - off] : 0;
        __syncthreads();
        s[t] += u;
        __syncthreads();
    }
    if (i < NN) incl[i] = s[t];
    if (t == 1023) bsum[blockIdx.x] = s[1023];
}

__global__ void k_scan2(int* __restrict__ bsum, int* __restrict__ boff,
                        const int nb) {
    __shared__ int s[64];
    int t = threadIdx.x;
    s[t] = (t < nb) ? bsum[t] : 0;
    __syncthreads();
#pragma unroll
    for (int off = 1; off < 64; off <<= 1) {
        int u = (t >= off) ? s[t - off] : 0;
        __syncthreads();
        s[t] += u;
        __syncthreads();
    }
    if (t < nb) boff[t] = s[t] - bsum[t];
    if (t == 63) boff[nb] = s[63];
}

__global__ void k_scan3(const int* __restrict__ cnt, const int* __restrict__ incl,
                        const int* __restrict__ boff, int* __restrict__ row_ptr,
                        const int nb) {
    int i = blockIdx.x * 1024 + threadIdx.x;
    if (i < NN) row_ptr[i] = incl[i] - cnt[i] + boff[blockIdx.x];
    if (i == 0) row_ptr[NN] = boff[nb];
}

// Phase 2: one block per bucket; per-node cursors in LDS; srcs writes land in
// the bucket's contiguous ~16KB region (write-back ~= useful bytes).
__global__ void k_fill2(const unsigned int* __restrict__ pairs,
                        const int* __restrict__ row_ptr,
                        const int* __restrict__ bcur, int* __restrict__ srcs) {
    __shared__ int cur[256];
    int b = blockIdx.x;
    int t = threadIdx.x;
    int node = (b << 8) + t;
    cur[t] = (node < NN) ? row_ptr[node] : 0;
    __syncthreads();
    int count = bcur[b];
    if (count > BPAD) count = BPAD;
    const unsigned int* pp = pairs + (size_t)b * BPAD;
    for (int i = t; i < count; i += 256) {
        unsigned int v = pp[i];
        int pos = atomicAdd(&cur[v & 255u], 1);
        srcs[pos] = (int)(v >> 16);
    }
}

// ---------------------------------------------------------------------------
// fp32 -> f16 hi/lo planes. Each thread: 4 features (float4 -> 2x f16x4).
__global__ void k_cvt_x(const float* __restrict__ x, unsigned short* __restrict__ xh,
                        unsigned short* __restrict__ xl) {
    int i = blockIdx.x * 256 + threadIdx.x;
    float4 v = ((const float4*)x)[i];
    float f[4] = {v.x, v.y, v.z, v.w};
    f16x4 h, l;
#pragma unroll
    for (int j = 0; j < 4; ++j) {
        _Float16 hh = (_Float16)f[j];
        h[j] = hh;
        l[j] = (_Float16)(f[j] - (float)hh);
    }
    *(f16x4*)(xh + (size_t)i * 4) = h;
    *(f16x4*)(xl + (size_t)i * 4) = l;
}

// All three layers' B tensors in MFMA-fragment-major order, one launch.
__global__ void k_cvt_w3(const float* __restrict__ w1l, const float* __restrict__ w1r,
                         const float* __restrict__ w2l, const float* __restrict__ w2r,
                         const float* __restrict__ w3l, const float* __restrict__ w3r,
                         unsigned short* __restrict__ bt1h, unsigned short* __restrict__ bt1l,
                         unsigned short* __restrict__ bt2h, unsigned short* __restrict__ bt2l,
                         unsigned short* __restrict__ bt3h, unsigned short* __restrict__ bt3l) {
    int ks = blockIdx.x, nt = blockIdx.y, layer = blockIdx.z;
    const int NT = (layer == 2) ? 3 : 8;
    const int NC = (layer == 2) ? NCLS : DD;
    if (nt >= NT) return;
    const float* wl = (layer == 0) ? w1l : (layer == 1) ? w2l : w3l;
    const float* wr = (layer == 0) ? w1r : (layer == 1) ? w2r : w3r;
    unsigned short* bh = (layer == 0) ? bt1h : (layer == 1) ? bt2h : bt3h;
    unsigned short* bl = (layer == 0) ? bt1l : (layer == 1) ? bt2l : bt3l;
    int lane = threadIdx.y, j = threadIdx.x;
    int row = nt * 16 + (lane & 15);          // output column n
    int k = ks * 32 + (lane >> 4) * 8 + j;    // K position in [Wl;Wr]
    float v = 0.f;
    if (row < NC)
        v = (k < 128) ? wl[(size_t)k * NC + row] : wr[(size_t)(k - 128) * NC + row];
    _Float16 h = (_Float16)v;
    _Float16 l = (_Float16)(v - (float)h);
    size_t o = ((size_t)(ks * NT + nt) * 64 + lane) * 8 + j;
    union { _Float16 f; unsigned short u; } ch, cl;
    ch.f = h; cl.f = l;
    bh[o] = ch.u;
    bl[o] = cl.u;
}

// ---------------------------------------------------------------------------
// Mean aggregation, hi-plane in -> hi-plane out.
__global__ void k_agg(const unsigned int* __restrict__ inh, const int* __restrict__ row_ptr,
                      const int* __restrict__ srcs, unsigned int* __restrict__ oh) {
    int node = blockIdx.x * 4 + (threadIdx.x >> 6);
    if (node >= NN) return;
    int lane = threadIdx.x & 63;
    int b = row_ptr[node], e = row_ptr[node + 1];
    float a0 = 0.f, a1 = 0.f;
    int i = b;
    for (; i + 3 < e; i += 4) {
        int s0 = srcs[i + 0], s1 = srcs[i + 1], s2 = srcs[i + 2], s3 = srcs[i + 3];
        unsigned int p0 = inh[(size_t)s0 * 64 + lane];
        unsigned int p1 = inh[(size_t)s1 * 64 + lane];
        unsigned int p2 = inh[(size_t)s2 * 64 + lane];
        unsigned int p3 = inh[(size_t)s3 * 64 + lane];
        float u0, u1;
        unpack2h(p0, u0, u1); a0 += u0; a1 += u1;
        unpack2h(p1, u0, u1); a0 += u0; a1 += u1;
        unpack2h(p2, u0, u1); a0 += u0; a1 += u1;
        unpack2h(p3, u0, u1); a0 += u0; a1 += u1;
    }
    for (; i < e; ++i) {
        unsigned int p = inh[(size_t)srcs[i] * 64 + lane];
        float u0, u1;
        unpack2h(p, u0, u1); a0 += u0; a1 += u1;
    }
    int deg = e - b;
    float inv = 1.0f / (float)(deg > 0 ? deg : 1);
    oh[(size_t)node * 64 + lane] = pack2h((_Float16)(a0 * inv), (_Float16)(a1 * inv));
}

// ---------------------------------------------------------------------------
// Split-precision f16 MFMA GEMM, B staged in LDS in fragment layout.
// A1 (agg): hi plane only (2-product); A2 (self): hi+lo (3-product).
template <int NT, int KPS, bool PACKOUT>
__launch_bounds__(256, 4)
__global__ void k_mfma(const unsigned short* __restrict__ A1h,
                       const unsigned short* __restrict__ A2h, const unsigned short* __restrict__ A2l,
                       const unsigned short* __restrict__ Bthf, const unsigned short* __restrict__ Btlf,
                       const float* __restrict__ bias, float* __restrict__ outf,
                       unsigned short* __restrict__ outh, unsigned short* __restrict__ outl,
                       const int NC) {
    constexpr int STAGE_ELEMS = KPS * NT * 64 * 8;
    constexpr int STAGE_U4 = STAGE_ELEMS / 8;
    __shared__ unsigned short sBh[STAGE_ELEMS];
    __shared__ unsigned short sBl[STAGE_ELEMS];

    const int tid = threadIdx.x;
    const int wave = tid >> 6, lane = tid & 63;
    const int quad = lane >> 4, mr = lane & 15;
    const int m0 = blockIdx.x * 64 + wave * 16;
    const int row = m0 + mr;
    const bool rok = row < NN;

    f32x4 acc[NT] = {};
    const f16x8 zero = {};

    auto aload = [&](int ks, f16x8& ah, f16x8& al) {
        const int ko = ((ks * 32) & 127) + quad * 8;
        if (ks < 4) {
            ah = rok ? *(const f16x8*)(A1h + (size_t)row * 128 + ko) : zero;
            al = zero;
        } else {
            ah = rok ? *(const f16x8*)(A2h + (size_t)row * 128 + ko) : zero;
            al = rok ? *(const f16x8*)(A2l + (size_t)row * 128 + ko) : zero;
        }
    };

    f16x8 cah, cal, pah, pal;
    aload(0, cah, cal);

#pragma unroll
    for (int s = 0; s < 8 / KPS; ++s) {
        const uint4* gh = (const uint4*)(Bthf + (size_t)s * STAGE_ELEMS);
        const uint4* gl = (const uint4*)(Btlf + (size_t)s * STAGE_ELEMS);
        uint4* lh = (uint4*)sBh;
        uint4* ll = (uint4*)sBl;
        if (s) __syncthreads();
        for (int i = tid; i < STAGE_U4; i += 256) {
            lh[i] = gh[i];
            ll[i] = gl[i];
        }
        __syncthreads();

#pragma unroll
        for (int kl = 0; kl < KPS; ++kl) {
            const int ks = s * KPS + kl;
            if (ks < 7) aload(ks + 1, pah, pal);
#pragma unroll
            for (int n = 0; n < NT; ++n) {
                const int fo = ((kl * NT + n) * 64 + lane) * 8;
                f16x8 bh = *(const f16x8*)(sBh + fo);
                f16x8 bl = *(const f16x8*)(sBl + fo);
                acc[n] = __builtin_amdgcn_mfma_f32_16x16x32_f16(cah, bh, acc[n], 0, 0, 0);
                acc[n] = __builtin_amdgcn_mfma_f32_16x16x32_f16(cah, bl, acc[n], 0, 0, 0);
                if (ks >= 4)
                    acc[n] = __builtin_amdgcn_mfma_f32_16x16x32_f16(cal, bh, acc[n], 0, 0, 0);
            }
            cah = pah;
            cal = pal;
        }
    }

#pragma unroll
    for (int n = 0; n < NT; ++n) {
        int col = n * 16 + mr;
        float bv = (col < NC) ? bias[col] : 0.f;
#pragma unroll
        for (int r = 0; r < 4; ++r) {
            int orow = m0 + quad * 4 + r;
            if (orow < NN && col < NC) {
                float v = acc[n][r] + bv;
                v = v > 0.f ? v : 0.f;
                if (PACKOUT) {
                    _Float16 h = (_Float16)v;
                    _Float16 l = (_Float16)(v - (float)h);
                    union { _Float16 f; unsigned short u; } ch, cl;
                    ch.f = h; cl.f = l;
                    outh[(size_t)orow * 128 + col] = ch.u;
                    outl[(size_t)orow * 128 + col] = cl.u;
                } else {
                    outf[(size_t)orow * NC + col] = v;
                }
            }
        }
    }
}

// ---------------------------------------------------------------------------
extern "C" void kernel_launch(void* const* d_in, const int* in_sizes, int n_in,
                              void* d_out, int out_size, void* d_ws, size_t ws_size,
                              hipStream_t stream) {
    const float* x    = (const float*)d_in[0];
    const int*   ei   = (const int*)d_in[1];
    const float* w1_l = (const float*)d_in[2];
    const float* w1_r = (const float*)d_in[3];
    const float* b1   = (const float*)d_in[4];
    const float* w2_l = (const float*)d_in[5];
    const float* w2_r = (const float*)d_in[6];
    const float* b2   = (const float*)d_in[7];
    const float* w3_l = (const float*)d_in[8];
    const float* w3_r = (const float*)d_in[9];
    const float* b3   = (const float*)d_in[10];
    float* out = (float*)d_out;

    char* w = (char*)d_ws;
    size_t off = 0;
    auto alloc = [&](size_t bytes) -> void* {
        void* p = w + off;
        off += (bytes + 255) / 256 * 256;
        return p;
    };
    int* flag    = (int*)alloc(4);
    int* cnt     = (int*)alloc((size_t)NN * 4);
    int* row_ptr = (int*)alloc((size_t)(NN + 1) * 4);
    int* srcs    = (int*)alloc((size_t)NE * 4);
    int* incl    = (int*)alloc((size_t)NN * 4);
    int* bsum    = (int*)alloc(64 * 4);
    int* boff    = (int*)alloc(64 * 4);
    int* bcur    = (int*)alloc((size_t)NBK * 4);
    unsigned int* pairs = (unsigned int*)alloc((size_t)NBK * BPAD * 4);
    unsigned short* xh   = (unsigned short*)alloc((size_t)NN * DD * 2);  // also h2h
    unsigned short* xl   = (unsigned short*)alloc((size_t)NN * DD * 2);  // also h2l
    unsigned short* aggh = (unsigned short*)alloc((size_t)NN * DD * 2);
    unsigned short* h1h  = (unsigned short*)alloc((size_t)NN * DD * 2);
    unsigned short* h1l  = (unsigned short*)alloc((size_t)NN * DD * 2);
    unsigned short* bt1h = (unsigned short*)alloc((size_t)8 * 8 * 64 * 8 * 2);
    unsigned short* bt1l = (unsigned short*)alloc((size_t)8 * 8 * 64 * 8 * 2);
    unsigned short* bt2h = (unsigned short*)alloc((size_t)8 * 8 * 64 * 8 * 2);
    unsigned short* bt2l = (unsigned short*)alloc((size_t)8 * 8 * 64 * 8 * 2);
    unsigned short* bt3h = (unsigned short*)alloc((size_t)8 * 3 * 64 * 8 * 2);
    unsigned short* bt3l = (unsigned short*)alloc((size_t)8 * 3 * 64 * 8 * 2);
    unsigned short* h2h = xh, *h2l = xl;  // x dead after layer-1 GEMM
    (void)ws_size;

    const int nb = (NN + 1023) / 1024;  // 49
    const int pb = (NE + EPB - 1) / EPB;  // 196
    k_init<<<(NN + 255) / 256, 256, 0, stream>>>(ei, flag, cnt, bcur);
    k_part<<<pb, 256, 0, stream>>>(ei, flag, cnt, bcur, pairs);
    k_scan1<<<nb, 1024, 0, stream>>>(cnt, incl, bsum);
    k_scan2<<<1, 64, 0, stream>>>(bsum, boff, nb);
    k_scan3<<<nb, 1024, 0, stream>>>(cnt, incl, boff, row_ptr, nb);
    k_fill2<<<NBK, 256, 0, stream>>>(pairs, row_ptr, bcur, srcs);

    k_cvt_x<<<(NN * DD / 4) / 256, 256, 0, stream>>>(x, xh, xl);
    k_cvt_w3<<<dim3(8, 8, 3), dim3(8, 64), 0, stream>>>(w1_l, w1_r, w2_l, w2_r,
                                                        w3_l, w3_r, bt1h, bt1l,
                                                        bt2h, bt2l, bt3h, bt3l);

    const int gmb = (NN + 63) / 64;   // 782 (GEMM m-blocks)
    const int gab = (NN + 3) / 4;     // 12500 (agg blocks, 4 nodes each)
    // Layer 1
    k_agg<<<gab, 256, 0, stream>>>((const unsigned int*)xh, row_ptr, srcs,
                                   (unsigned int*)aggh);
    k_mfma<8, 2, true><<<gmb, 256, 0, stream>>>(aggh, xh, xl, bt1h, bt1l, b1,
                                                nullptr, h1h, h1l, DD);
    // Layer 2 (h2 planes alias x planes; x is dead)
    k_agg<<<gab, 256, 0, stream>>>((const unsigned int*)h1h, row_ptr, srcs,
                                   (unsigned int*)aggh);
    k_mfma<8, 2, true><<<gmb, 256, 0, stream>>>(aggh, h1h, h1l, bt2h, bt2l, b2,
                                                nullptr, h2h, h2l, DD);
    // Layer 3
    k_agg<<<gab, 256, 0, stream>>>((const unsigned int*)h2h, row_ptr, srcs,
                                   (unsigned int*)aggh);
    k_mfma<3, 2, false><<<gmb, 256, 0, stream>>>(aggh, h2h, h2l, bt3h, bt3l, b3,
                                                 out, nullptr, nullptr, NCLS);
}